// Round 13
// baseline (3533.558 us; speedup 1.0000x reference)
//
#include <hip/hip_runtime.h>
#include <hip/hip_bf16.h>
#include <stdint.h>

typedef __bf16 bf16_t;
typedef __bf16 bf16x8 __attribute__((ext_vector_type(8)));
typedef __bf16 bf16x4 __attribute__((ext_vector_type(4)));
typedef float  f32x4  __attribute__((ext_vector_type(4)));
typedef float  f32x16 __attribute__((ext_vector_type(16)));

#define SEQ   512
#define BATCH 32
#define HID   1024
#define FFD   4096
#define NROW  (SEQ*BATCH)          /* 16384 rows */
#define NTOT  ((long)NROW*HID)     /* 16,777,216 */
#define QKVS  3072

typedef __attribute__((address_space(3))) uint32_t lds_u32;
typedef __attribute__((address_space(1))) const uint32_t glb_u32;

__device__ __forceinline__ void gload_lds16(const void* g, void* l) {
  glb_u32* gp = reinterpret_cast<glb_u32*>(reinterpret_cast<uintptr_t>(g));
  lds_u32* lp = reinterpret_cast<lds_u32*>(reinterpret_cast<uintptr_t>(l));
  __builtin_amdgcn_global_load_lds(gp, lp, 16, 0, 0);
}
#define BAR() asm volatile("s_barrier" ::: "memory")

// ------------- embedding: hb = bf16(emb[x]*32 + pos[s]) --------------------
__global__ __launch_bounds__(256) void embed_k(const int* __restrict__ x,
    const float* __restrict__ emb, const float* __restrict__ pos,
    bf16_t* __restrict__ hb)
{
  const long row = blockIdx.x;           // row = s*32 + b
  const int  s   = (int)(row >> 5);
  const long idx = x[row];
  const int  t   = threadIdx.x;
  float4 e  = ((const float4*)(emb + idx*HID))[t];
  float4 pv = ((const float4*)(pos + (long)s*HID))[t];
  bf16x4 ob = {(bf16_t)(e.x*32.f+pv.x), (bf16_t)(e.y*32.f+pv.y),
               (bf16_t)(e.z*32.f+pv.z), (bf16_t)(e.w*32.f+pv.w)};
  *(bf16x4*)(hb + row*HID + (long)t*4) = ob;
}

// ---- inline stats: reduce np partial (sum,sumsq) pairs -> mean, rstd ------
__device__ __forceinline__ void stats_reduce(const float* __restrict__ part,
    int np, double* shd, float& mS, float& rS, int nthr)
{
  if (np == 0) { mS = 0.f; rS = 1.f; return; }
  const int tid = threadIdx.x;
  double s = 0.0, s2 = 0.0;
  for (int i = tid; i < np; i += nthr) { s += (double)part[2*i]; s2 += (double)part[2*i+1]; }
#pragma unroll
  for (int o = 1; o < 64; o <<= 1) { s += __shfl_xor(s, o); s2 += __shfl_xor(s2, o); }
  __syncthreads();                      // LDS scratch safe to overwrite
  const int w = tid >> 6, nw = nthr >> 6;
  if ((tid & 63) == 0) { shd[w] = s; shd[8 + w] = s2; }
  __syncthreads();
  double ts = 0.0, ts2 = 0.0;
  for (int i = 0; i < nw; ++i) { ts += shd[i]; ts2 += shd[8 + i]; }
  const double mean = ts / (double)NTOT;
  const double var  = ts2 / (double)NTOT - mean*mean;
  mS = (float)mean;
  rS = (float)(1.0 / sqrt(var + 1e-5));
}

// ---- LDS-free weight convert+transpose, 512-thread version (prep0) --------
__device__ __forceinline__ void wcvtNL_body(const float* __restrict__ W,
    bf16_t* __restrict__ wT, int K, int N, int bid)
{
  const int t  = threadIdx.x;                 // 0..511
  const int nt = N >> 9;
  const int n  = ((bid % nt) << 9) + t;
  const int k0 = (bid / nt) << 6;
#pragma unroll
  for (int kb = 0; kb < 64; kb += 8) {
    bf16x8 o;
#pragma unroll
    for (int j = 0; j < 8; ++j)
      o[j] = (bf16_t)W[(long)(k0 + kb + j)*N + n];
    *(bf16x8*)&wT[(long)n*K + k0 + kb] = o;
  }
}

// ---- 256-thread variant (rides inside the attention dispatch) -------------
__device__ __forceinline__ void wcvt256(const float* __restrict__ W,
    bf16_t* __restrict__ wT, int K, int N, int bid)
{
  const int t  = threadIdx.x;                 // 0..255
  const int nt = N >> 8;
  const int n  = ((bid % nt) << 8) + t;
  const int k0 = (bid / nt) << 6;
#pragma unroll
  for (int kb = 0; kb < 64; kb += 8) {
    bf16x8 o;
#pragma unroll
    for (int j = 0; j < 8; ++j)
      o[j] = (bf16_t)W[(long)(k0 + kb + j)*N + n];
    *(bf16x8*)&wT[(long)n*K + k0 + kb] = o;
  }
}

// prologue: layer-0 QKV weights (96 cvt blocks) + cs3 (6 blocks)
__global__ __launch_bounds__(512) void prep0(const float* __restrict__ wq,
    const float* __restrict__ wk, const float* __restrict__ wv,
    bf16_t* __restrict__ wT3, float* __restrict__ cs3)
{
  const int b = blockIdx.x;
  if (b < 96) {
    const int sel = b >> 5;
    const float* W = sel == 0 ? wq : sel == 1 ? wk : wv;
    wcvtNL_body(W, wT3 + (size_t)sel*HID*HID, HID, HID, b & 31);
  } else {
    const int col = (b - 96)*512 + threadIdx.x;
    const int sel = col >> 10, n = col & 1023;
    const float* W = sel == 0 ? wq : sel == 1 ? wk : wv;
    float s = 0.f;
    for (int k = 0; k < HID; ++k) s += W[(long)k*HID + n];
    cs3[col] = s;
  }
}

// ====== bf16 MFMA GEMM, 128x256 tile, BK=64, 8 waves, 32x32x16, LN-fold ====
// MODE 3: out = bf16( rstd*acc + (bias - mean*rstd*cs[col]) )          (QKV)
// MODE 4: out = bf16( relu(same) )                                     (FFN1)
// MODE 5: out = bf16( acc + bias + (res-mean)*rstd ); LN partials      (wo/FFN2)
template<int MODE>
__global__ __launch_bounds__(512, 4)
void gemmW(const bf16_t* __restrict__ A, const bf16_t* __restrict__ Bt,
           const float* __restrict__ ba, const float* __restrict__ bb,
           const float* __restrict__ bc, const float* __restrict__ cs,
           const float* __restrict__ partIn, int npIn,
           const bf16_t* __restrict__ res,
           bf16_t* __restrict__ outB, float* __restrict__ part,
           int M, int N, int K)
{
  __shared__ bf16_t As[128][64];
  __shared__ bf16_t Bs[256][64];
  __shared__ float  rs[512], rq[512];
  const int tid = threadIdx.x;
  const int w = tid >> 6, l = tid & 63;
  const int wm = w >> 2, wn = w & 3;
  const int lr = l & 31, hi = l >> 5;

  const int nbn = N >> 8;
  const int nwg = gridDim.x;
  const int q8 = nwg >> 3, r8 = nwg & 7;
  const int xcd = blockIdx.x & 7, bidx = blockIdx.x >> 3;
  const int wg = (xcd < r8 ? xcd*(q8+1) : r8*(q8+1) + (xcd-r8)*q8) + bidx;
  const long bm = wg / nbn, bn = wg % nbn;
  const long rA0 = bm << 7, rB0 = bn << 8;

  const int srow   = tid >> 3;
  const int schunk = (((tid & 7) ^ ((tid >> 3) & 7)) << 3);
  const int ldsw   = (tid >> 6) << 10;

  f32x16 a00 = {0}, a01 = {0}, a10 = {0}, a11 = {0};

#define STG_TILE(kt) do { \
    const long kb_ = (long)(kt)*64 + schunk; \
    gload_lds16(A  + (rA0 + srow)*(long)K + kb_,        (char*)As + ldsw); \
    gload_lds16(A  + (rA0 + 64 + srow)*(long)K + kb_,   (char*)As + 8192 + ldsw); \
    gload_lds16(Bt + (rB0 + srow)*(long)K + kb_,        (char*)Bs + ldsw); \
    gload_lds16(Bt + (rB0 + 64 + srow)*(long)K + kb_,   (char*)Bs + 8192 + ldsw); \
    gload_lds16(Bt + (rB0 + 128 + srow)*(long)K + kb_,  (char*)Bs + 16384 + ldsw); \
    gload_lds16(Bt + (rB0 + 192 + srow)*(long)K + kb_,  (char*)Bs + 24576 + ldsw); \
  } while (0)
#define FRA(mt, kk) (*(const bf16x8*)((const char*)As + (wm*64 + (mt)*32 + lr)*128 + \
                      ((((kk)*2 + hi) ^ (l & 7)) << 4)))
#define FRB(nt, kk) (*(const bf16x8*)((const char*)Bs + (wn*64 + (nt)*32 + lr)*128 + \
                      ((((kk)*2 + hi) ^ (l & 7)) << 4)))

  const int nk = K >> 6;
  for (int t = 0; t < nk; ++t) {
    __syncthreads();
    STG_TILE(t);
    __syncthreads();
#pragma unroll
    for (int kk = 0; kk < 4; ++kk) {
      bf16x8 fa0 = FRA(0, kk), fa1 = FRA(1, kk);
      bf16x8 fb0 = FRB(0, kk), fb1 = FRB(1, kk);
      a00 = __builtin_amdgcn_mfma_f32_32x32x16_bf16(fa0, fb0, a00, 0, 0, 0);
      a01 = __builtin_amdgcn_mfma_f32_32x32x16_bf16(fa0, fb1, a01, 0, 0, 0);
      a10 = __builtin_amdgcn_mfma_f32_32x32x16_bf16(fa1, fb0, a10, 0, 0, 0);
      a11 = __builtin_amdgcn_mfma_f32_32x32x16_bf16(fa1, fb1, a11, 0, 0, 0);
    }
  }
#undef STG_TILE
#undef FRA
#undef FRB

  // inline stats (reuses As as f64 scratch; barrier inside protects K-loop reads)
  float mS, rS;
  stats_reduce(partIn, npIn, (double*)&As[0][0], mS, rS, 512);

  const bool q3 = (N == 3072);
  float ls = 0.f, lsq = 0.f;
  const long rowT = rA0 + wm*64 + 4*hi;
  const long colT = rB0 + wn*64 + lr;
#pragma unroll
  for (int nt = 0; nt < 2; ++nt) {
    const long col = colT + nt*32;
    float bv;
    if (MODE == 3 && q3)
      bv = col < 1024 ? ba[col] : col < 2048 ? bb[col - 1024] : bc[col - 2048];
    else
      bv = ba[col];
    float beta = 0.f;
    if (MODE == 3 || MODE == 4) beta = bv - mS*rS*cs[col];
#pragma unroll
    for (int mt = 0; mt < 2; ++mt) {
      const f32x16 acc = mt == 0 ? (nt == 0 ? a00 : a01) : (nt == 0 ? a10 : a11);
#pragma unroll
      for (int r = 0; r < 16; ++r) {
        const long row = rowT + mt*32 + (r & 3) + 8*(r >> 2);
        const long off = row*(long)N + col;
        float v;
        if (MODE == 3)      v = fmaf(acc[r], rS, beta);
        else if (MODE == 4) v = fmaxf(fmaf(acc[r], rS, beta), 0.f);
        else {
          v = acc[r] + bv + ((float)res[off] - mS)*rS;
          ls += v; lsq += v*v;
        }
        outB[off] = (bf16_t)v;
      }
    }
  }
  if (MODE == 5) {
    rs[tid] = ls; rq[tid] = lsq;
    __syncthreads();
    for (int o = 256; o > 0; o >>= 1) {
      if (tid < o) { rs[tid] += rs[tid+o]; rq[tid] += rq[tid+o]; }
      __syncthreads();
    }
    if (tid == 0) { part[2*blockIdx.x] = rs[0]; part[2*blockIdx.x + 1] = rq[0]; }
  }
}

// ========== MFMA attention (blocks 0..255) + prep ride-along (256+) ========
// Attention: r11-proven 4-wave version. Prep blocks are LDS-free and rotate
// through the spare CU slot (attn = 1 block/CU, LDS caps residency at 2).
__global__ __launch_bounds__(256) void attn_m(
    const bf16_t* __restrict__ qkv, bf16_t* __restrict__ ob,
    const float* __restrict__ Wo, bf16_t* __restrict__ wTo,
    const float* __restrict__ W1, bf16_t* __restrict__ wT1, float* __restrict__ cs1,
    const float* __restrict__ W2, bf16_t* __restrict__ wT2,
    const float* __restrict__ Wq, const float* __restrict__ Wk,
    const float* __restrict__ Wv, bf16_t* __restrict__ wT3,
    float* __restrict__ cs3)
{
  if (blockIdx.x >= 256) {               // ---- prep ride-along ----
    const int b2 = blockIdx.x - 256;
    if (b2 < 64)        wcvt256(Wo, wTo, 1024, 1024, b2);
    else if (b2 < 320)  wcvt256(W1, wT1, 1024, 4096, b2 - 64);
    else if (b2 < 576)  wcvt256(W2, wT2, 4096, 1024, b2 - 320);
    else if (b2 < 592) {                 // cs1 = colsum(W1)
      const int n = (b2 - 576)*256 + threadIdx.x;
      float s0 = 0.f, s1 = 0.f, s2 = 0.f, s3 = 0.f;
      for (int k = 0; k < 1024; k += 4) {
        s0 += W1[(long)k*4096 + n];       s1 += W1[(long)(k+1)*4096 + n];
        s2 += W1[(long)(k+2)*4096 + n];   s3 += W1[(long)(k+3)*4096 + n];
      }
      cs1[n] = (s0 + s1) + (s2 + s3);
    } else if (b2 < 784) {               // next-layer QKV cvt
      const int i = b2 - 592, sel = i >> 6;
      const float* W = sel == 0 ? Wq : sel == 1 ? Wk : Wv;
      wcvt256(W, wT3 + (size_t)sel*HID*HID, 1024, 1024, i & 63);
    } else {                             // cs3 = colsum(next QKV)
      const int col = (b2 - 784)*256 + threadIdx.x;
      const int sel = col >> 10, n = col & 1023;
      const float* W = sel == 0 ? Wq : sel == 1 ? Wk : Wv;
      float s0 = 0.f, s1 = 0.f, s2 = 0.f, s3 = 0.f;
      for (int k = 0; k < 1024; k += 4) {
        s0 += W[(long)k*1024 + n];        s1 += W[(long)(k+1)*1024 + n];
        s2 += W[(long)(k+2)*1024 + n];    s3 += W[(long)(k+3)*1024 + n];
      }
      cs3[col] = (s0 + s1) + (s2 + s3);
    }
    return;
  }

  // ---------------- attention proper (r11 version) -------------------------
  __shared__ __align__(16) bf16_t Qb[2][8192];   // 32 KB
  __shared__ __align__(16) bf16_t Kb[2][8192];   // 32 KB
  __shared__ __align__(16) bf16_t Ps[4096];      // 8 KB
  bf16_t* Vs = &Qb[0][0];                        // [128][64] (phase 2)
  bf16_t* Os = &Kb[0][0];                        // [64][128] (phase 2)

  const int tid = threadIdx.x;
  const int w = tid >> 6, l = tid & 63;
  const int fr = l & 15, kq = l >> 4;
  const int head = blockIdx.x & 7, b = blockIdx.x >> 3;
  const long rbase = (long)head*32 + b;

  const int lr  = tid >> 2;                      // staging row 0..63
  const int sslot = (tid & 15) ^ (tid >> 4);     // pre-swizzled Q/K src slot

  f32x4 accS[4] = {{0,0,0,0},{0,0,0,0},{0,0,0,0},{0,0,0,0}};

#define STAGE_QK(qb, kb, kc) do { \
    _Pragma("unroll") for (int i_ = 0; i_ < 4; ++i_) { \
      const int r_ = i_*16 + (tid >> 4); \
      const long gq_ = ((long)r_*256 + rbase)*QKVS + (kc) + sslot*8; \
      gload_lds16(qkv + gq_,        (char*)(qb) + i_*4096 + w*1024); \
      gload_lds16(qkv + gq_ + 1024, (char*)(kb) + i_*4096 + w*1024); \
    } } while (0)

  // ---------------- phase 1: S = Q.K^T over K=1024, double-buffered --------
  STAGE_QK(Qb[0], Kb[0], 0);
#pragma unroll
  for (int c = 0; c < 8; ++c) {
    const int cur = c & 1;
    if (c < 7) {
      STAGE_QK(Qb[cur ^ 1], Kb[cur ^ 1], (c + 1)*128);
      asm volatile("s_waitcnt vmcnt(8)" ::: "memory");
    } else {
      asm volatile("s_waitcnt vmcnt(0)" ::: "memory");
    }
    BAR();                                       // chunk c resident
#pragma unroll
    for (int kk = 0; kk < 4; ++kk) {
      const int ra = w*16 + fr;
      bf16x8 a = *(const bf16x8*)&Qb[cur][ra*128 + (((kk*4 + kq) ^ fr) << 3)];
#pragma unroll
      for (int n = 0; n < 4; ++n) {
        const int rb = n*16 + fr;
        bf16x8 bv = *(const bf16x8*)&Kb[cur][rb*128 + (((kk*4 + kq) ^ fr) << 3)];
        accS[n] = __builtin_amdgcn_mfma_f32_16x16x32_bf16(a, bv, accS[n], 0, 0, 0);
      }
    }
    BAR();                                       // all reads done before restage
  }
#undef STAGE_QK

  // ---------------- softmax (rows live in 16-lane groups) ------------------
  const float scale = 0.08838834764831843f;      // 1/sqrt(128)
  float pj[4][4];
#pragma unroll
  for (int j = 0; j < 4; ++j) {
    float m = fmaxf(fmaxf(accS[0][j], accS[1][j]), fmaxf(accS[2][j], accS[3][j]));
    m = fmaxf(m, __shfl_xor(m, 1));
    m = fmaxf(m, __shfl_xor(m, 2));
    m = fmaxf(m, __shfl_xor(m, 4));
    m = fmaxf(m, __shfl_xor(m, 8));
    m *= scale;
    float s = 0.f;
#pragma unroll
    for (int n = 0; n < 4; ++n) { pj[n][j] = __expf(accS[n][j]*scale - m); s += pj[n][j]; }
    s += __shfl_xor(s, 1);
    s += __shfl_xor(s, 2);
    s += __shfl_xor(s, 4);
    s += __shfl_xor(s, 8);
    const float rv = 1.f / s;
#pragma unroll
    for (int n = 0; n < 4; ++n) pj[n][j] *= rv;
  }
#pragma unroll
  for (int n = 0; n < 4; ++n)
#pragma unroll
    for (int j = 0; j < 4; ++j) {
      const int r = w*16 + kq*4 + j;
      const int cpos = n*16 + fr;
      Ps[r*64 + (((cpos >> 3) ^ (r & 7)) << 3) + (cpos & 7)] = (bf16_t)pj[n][j];
    }
  __syncthreads();                               // P visible; Qb/Kb free

  // ---------------- phase 2: O = P.V, 128-feature chunks, V prefetch -------
  const long orow = (long)lr*256 + b*8 + head;
  const bf16_t* vbase = qkv + ((long)lr*256 + rbase)*QKVS + 2048;
  const int ra2 = w*16 + fr;
  bf16x8 a0 = *(const bf16x8*)&Ps[ra2*64 + ((kq       ^ (ra2 & 7)) << 3)];
  bf16x8 a1 = *(const bf16x8*)&Ps[ra2*64 + (((4 + kq) ^ (ra2 & 7)) << 3)];

  uint4 vr[4];
#pragma unroll
  for (int i = 0; i < 4; ++i)
    vr[i] = *(const uint4*)&vbase[(tid & 3)*8 + i*32];

#pragma unroll
  for (int fc8 = 0; fc8 < 8; ++fc8) {
    // transpose-write current V chunk into Vs[f][s] (slot-swizzled)
#pragma unroll
    for (int i = 0; i < 4; ++i) {
      const int f0 = (tid & 3)*8 + i*32;
      const bf16_t* ve = (const bf16_t*)&vr[i];
#pragma unroll
      for (int j = 0; j < 8; ++j) {
        const int f = f0 + j;
        Vs[f*64 + (((lr >> 3) ^ (f & 7)) << 3) + (lr & 7)] = ve[j];
      }
    }
    __syncthreads();
    // prefetch next chunk's V into registers (hides under MFMA+Os)
    if (fc8 < 7) {
#pragma unroll
      for (int i = 0; i < 4; ++i)
        vr[i] = *(const uint4*)&vbase[(fc8 + 1)*128 + (tid & 3)*8 + i*32];
    }
    f32x4 accO[8];
#pragma unroll
    for (int nt = 0; nt < 8; ++nt) {
      const int f = nt*16 + fr;
      bf16x8 b0 = *(const bf16x8*)&Vs[f*64 + ((kq       ^ (f & 7)) << 3)];
      bf16x8 b1 = *(const bf16x8*)&Vs[f*64 + (((4 + kq) ^ (f & 7)) << 3)];
      accO[nt] = __builtin_amdgcn_mfma_f32_16x16x32_bf16(a0, b0, (f32x4){0.f,0.f,0.f,0.f}, 0, 0, 0);
      accO[nt] = __builtin_amdgcn_mfma_f32_16x16x32_bf16(a1, b1, accO[nt], 0, 0, 0);
    }
#pragma unroll
    for (int nt = 0; nt < 8; ++nt)
#pragma unroll
      for (int j = 0; j < 4; ++j) {
        const int r = w*16 + kq*4 + j;
        const int cpos = nt*16 + fr;
        Os[r*128 + (((cpos >> 3) ^ (r & 7)) << 3) + (cpos & 7)] = (bf16_t)accO[nt][j];
      }
    __syncthreads();
#pragma unroll
    for (int i = 0; i < 4; ++i) {
      const int p = (tid & 3)*4 + i;             // logical 16B slot 0..15
      uint4 vv = *(const uint4*)&Os[lr*128 + ((p ^ (lr & 7)) << 3)];
      *(uint4*)&ob[orow*HID + fc8*128 + p*8] = vv;
    }
  }
}

// -------- final: d_out(f32) = (t2_raw - mean)*rstd (inline stats) ----------
__global__ __launch_bounds__(256) void final_norm(const bf16_t* __restrict__ t,
    const float* __restrict__ part, int np, float* __restrict__ out)
{
  __shared__ double shd[16];
  float m, r;
  stats_reduce(part, np, shd, m, r, 256);
  const long n8 = NTOT / 8;
  for (long i = (long)blockIdx.x*blockDim.x + threadIdx.x; i < n8;
       i += (long)gridDim.x*blockDim.x) {
    bf16x8 v = ((const bf16x8*)t)[i];
    float4 o0 = {((float)v[0]-m)*r, ((float)v[1]-m)*r, ((float)v[2]-m)*r, ((float)v[3]-m)*r};
    float4 o1 = {((float)v[4]-m)*r, ((float)v[5]-m)*r, ((float)v[6]-m)*r, ((float)v[7]-m)*r};
    ((float4*)out)[2*i]   = o0;
    ((float4*)out)[2*i+1] = o1;
  }
}

// ---------------------------------------------------------------------------
extern "C" void kernel_launch(void* const* d_in, const int* in_sizes, int n_in,
                              void* d_out, int out_size, void* d_ws, size_t ws_size,
                              hipStream_t stream)
{
  const int*   x    = (const int*)  d_in[0];
  const float* emb  = (const float*)d_in[1];
  const float* pos  = (const float*)d_in[2];
  const float* wq_a = (const float*)d_in[3];
  const float* bq_a = (const float*)d_in[4];
  const float* wk_a = (const float*)d_in[5];
  const float* bk_a = (const float*)d_in[6];
  const float* wv_a = (const float*)d_in[7];
  const float* bv_a = (const float*)d_in[8];
  const float* wo_a = (const float*)d_in[9];
  const float* bo_a = (const float*)d_in[10];
  const float* w1_a = (const float*)d_in[11];
  const float* b1_a = (const float*)d_in[12];
  const float* w2_a = (const float*)d_in[13];
  const float* b2_a = (const float*)d_in[14];

  char* p = (char*)d_ws;
  auto take = [&](size_t n) { char* r = p; p += (n + 255) & ~(size_t)255; return r; };
  bf16_t* hb   = (bf16_t*)take(NTOT*2);                 // raw hidden (rolling)
  bf16_t* U    = (bf16_t*)take((size_t)NROW*FFD*2);     // 128 MB union
  bf16_t* qkv  = U;                                     // NROW x 3072
  bf16_t* attb = U + 3*NTOT;
  bf16_t* ffb  = U;                                     // overlays qkv (dead)
  bf16_t* wTo  = (bf16_t*)take((size_t)HID*HID*2);
  bf16_t* wT1  = (bf16_t*)take((size_t)HID*FFD*2);
  bf16_t* wT2  = (bf16_t*)take((size_t)HID*FFD*2);
  bf16_t* wT3  = (bf16_t*)take((size_t)3*HID*HID*2);
  float*  cs1  = (float*) take(FFD*4);
  float*  cs3  = (float*) take(QKVS*4);
  float*  part1= (float*) take(2048*4);
  float*  part2= (float*) take(2048*4);

  const int gQKV = (NROW/128)*(QKVS/256);   // 1536
  const int gH   = (NROW/128)*(HID/256);    // 512
  const int gF   = (NROW/128)*(FFD/256);    // 2048

  embed_k<<<NROW, 256, 0, stream>>>(x, emb, pos, hb);
  prep0<<<102, 512, 0, stream>>>(wq_a, wk_a, wv_a, wT3, cs3);

  for (int i = 0; i < 6; ++i) {
    const float* Bq = bq_a + (size_t)i*HID;
    const float* Bk = bk_a + (size_t)i*HID;
    const float* Bv = bv_a + (size_t)i*HID;
    const float* Wo = wo_a + (size_t)i*HID*HID;  const float* Bo = bo_a + (size_t)i*HID;
    const float* W1 = w1_a + (size_t)i*HID*FFD;  const float* B1 = b1_a + (size_t)i*FFD;
    const float* W2 = w2_a + (size_t)i*FFD*HID;  const float* B2 = b2_a + (size_t)i*HID;
    const int npIn = (i == 0) ? 0 : gH;          // identity at layer 0
    const int haveNext = (i < 5);
    const float* Wqn = wq_a + (size_t)(i+1 < 6 ? i+1 : 0)*HID*HID;
    const float* Wkn = wk_a + (size_t)(i+1 < 6 ? i+1 : 0)*HID*HID;
    const float* Wvn = wv_a + (size_t)(i+1 < 6 ? i+1 : 0)*HID*HID;

    // QKV projection (LN-fold; stats inlined from part2)
    gemmW<3><<<gQKV, 512, 0, stream>>>(hb, wT3, Bq, Bk, Bv, cs3, part2, npIn,
                                       nullptr, qkv, nullptr, NROW, QKVS, HID);

    // attention + LDS-free prep ride-along (this layer's Wo/W1/W2/cs1,
    // next layer's QKV cvt + cs3)
    attn_m<<<haveNext ? 1040 : 848, 256, 0, stream>>>(
        qkv, attb, Wo, wTo, W1, wT1, cs1, W2, wT2,
        Wqn, Wkn, Wvn, wT3, cs3);

    // wo projection + residual fold + LN partials -> part1
    gemmW<5><<<gH, 512, 0, stream>>>(attb, wTo, Bo, Bo, Bo, nullptr, part2, npIn,
                                     hb, hb, part1, NROW, HID, HID);

    // FFN1 (LN-fold + relu; stats from part1)
    gemmW<4><<<gF, 512, 0, stream>>>(hb, wT1, B1, B1, B1, cs1, part1, gH,
                                     nullptr, ffb, nullptr, NROW, FFD, HID);

    // FFN2 + residual fold + LN partials -> part2
    gemmW<5><<<gH, 512, 0, stream>>>(ffb, wT2, B2, B2, B2, nullptr, part1, gH,
                                     hb, hb, part2, NROW, HID, FFD);
  }

  final_norm<<<2048, 256, 0, stream>>>(hb, part2, gH, (float*)d_out);
}

// Round 14
// 3414.425 us; speedup vs baseline: 1.0349x; 1.0349x over previous
//
#include <hip/hip_runtime.h>
#include <hip/hip_bf16.h>
#include <stdint.h>

typedef __bf16 bf16_t;
typedef __bf16 bf16x8 __attribute__((ext_vector_type(8)));
typedef __bf16 bf16x4 __attribute__((ext_vector_type(4)));
typedef float  f32x4  __attribute__((ext_vector_type(4)));
typedef float  f32x16 __attribute__((ext_vector_type(16)));

#define SEQ   512
#define BATCH 32
#define HID   1024
#define FFD   4096
#define NROW  (SEQ*BATCH)          /* 16384 rows */
#define NTOT  ((long)NROW*HID)     /* 16,777,216 */
#define QKVS  3072

typedef __attribute__((address_space(3))) uint32_t lds_u32;
typedef __attribute__((address_space(1))) const uint32_t glb_u32;

__device__ __forceinline__ void gload_lds16(const void* g, void* l) {
  glb_u32* gp = reinterpret_cast<glb_u32*>(reinterpret_cast<uintptr_t>(g));
  lds_u32* lp = reinterpret_cast<lds_u32*>(reinterpret_cast<uintptr_t>(l));
  __builtin_amdgcn_global_load_lds(gp, lp, 16, 0, 0);
}
#define BAR() asm volatile("s_barrier" ::: "memory")

// ------------- embedding: hb = bf16(emb[x]*32 + pos[s]) --------------------
__global__ __launch_bounds__(256) void embed_k(const int* __restrict__ x,
    const float* __restrict__ emb, const float* __restrict__ pos,
    bf16_t* __restrict__ hb)
{
  const long row = blockIdx.x;           // row = s*32 + b
  const int  s   = (int)(row >> 5);
  const long idx = x[row];
  const int  t   = threadIdx.x;
  float4 e  = ((const float4*)(emb + idx*HID))[t];
  float4 pv = ((const float4*)(pos + (long)s*HID))[t];
  bf16x4 ob = {(bf16_t)(e.x*32.f+pv.x), (bf16_t)(e.y*32.f+pv.y),
               (bf16_t)(e.z*32.f+pv.z), (bf16_t)(e.w*32.f+pv.w)};
  *(bf16x4*)(hb + row*HID + (long)t*4) = ob;
}

// ---- inline stats: reduce np partial (sum,sumsq) pairs -> mean, rstd ------
__device__ __forceinline__ void stats_reduce(const float* __restrict__ part,
    int np, double* shd, float& mS, float& rS, int nthr)
{
  if (np == 0) { mS = 0.f; rS = 1.f; return; }
  const int tid = threadIdx.x;
  double s = 0.0, s2 = 0.0;
  for (int i = tid; i < np; i += nthr) { s += (double)part[2*i]; s2 += (double)part[2*i+1]; }
#pragma unroll
  for (int o = 1; o < 64; o <<= 1) { s += __shfl_xor(s, o); s2 += __shfl_xor(s2, o); }
  __syncthreads();                      // LDS scratch safe to overwrite
  const int w = tid >> 6, nw = nthr >> 6;
  if ((tid & 63) == 0) { shd[w] = s; shd[8 + w] = s2; }
  __syncthreads();
  double ts = 0.0, ts2 = 0.0;
  for (int i = 0; i < nw; ++i) { ts += shd[i]; ts2 += shd[8 + i]; }
  const double mean = ts / (double)NTOT;
  const double var  = ts2 / (double)NTOT - mean*mean;
  mS = (float)mean;
  rS = (float)(1.0 / sqrt(var + 1e-5));
}

// ---- LDS-free weight convert+transpose (512 threads/block) ----------------
__device__ __forceinline__ void wcvtNL_body(const float* __restrict__ W,
    bf16_t* __restrict__ wT, int K, int N, int bid)
{
  const int t  = threadIdx.x;                 // 0..511
  const int nt = N >> 9;
  const int n  = ((bid % nt) << 9) + t;
  const int k0 = (bid / nt) << 6;
#pragma unroll
  for (int kb = 0; kb < 64; kb += 8) {
    bf16x8 o;
#pragma unroll
    for (int j = 0; j < 8; ++j)
      o[j] = (bf16_t)W[(long)(k0 + kb + j)*N + n];
    *(bf16x8*)&wT[(long)n*K + k0 + kb] = o;
  }
}

// ---- column sums: out[col] = sum_k W[k][col]; 512 cols per block ----------
__device__ __forceinline__ void csum512_body(const float* __restrict__ W,
    float* __restrict__ out, int K, int N, int bid)
{
  const int n = bid*512 + threadIdx.x;
  float s0 = 0.f, s1 = 0.f, s2 = 0.f, s3 = 0.f;
  for (int k = 0; k < K; k += 4) {
    s0 += W[(long)k*N + n];
    s1 += W[(long)(k+1)*N + n];
    s2 += W[(long)(k+2)*N + n];
    s3 += W[(long)(k+3)*N + n];
  }
  out[n] = (s0 + s1) + (s2 + s3);
}

// prologue: layer-0 QKV weights (96 cvt blocks) + cs3 (6 blocks)
__global__ __launch_bounds__(512) void prep0(const float* __restrict__ wq,
    const float* __restrict__ wk, const float* __restrict__ wv,
    bf16_t* __restrict__ wT3, float* __restrict__ cs3)
{
  const int b = blockIdx.x;
  if (b < 96) {
    const int sel = b >> 5;
    const float* W = sel == 0 ? wq : sel == 1 ? wk : wv;
    wcvtNL_body(W, wT3 + (size_t)sel*HID*HID, HID, HID, b & 31);
  } else {
    const int col = (b - 96)*512 + threadIdx.x;
    const int sel = col >> 10, n = col & 1023;
    const float* W = sel == 0 ? wq : sel == 1 ? wk : wv;
    float s = 0.f;
    for (int k = 0; k < HID; ++k) s += W[(long)k*HID + n];
    cs3[col] = s;
  }
}

// ---- per-layer prep: Wo/W1/W2 cvt + cs1 [+ next QKV cvt + cs3] ------------
__global__ __launch_bounds__(512) void prep_k(
    const float* __restrict__ Wo, bf16_t* __restrict__ wTo,
    const float* __restrict__ W1, bf16_t* __restrict__ wT1, float* __restrict__ cs1,
    const float* __restrict__ W2, bf16_t* __restrict__ wT2,
    const float* __restrict__ Wq, const float* __restrict__ Wk,
    const float* __restrict__ Wv, bf16_t* __restrict__ wT3,
    float* __restrict__ cs3)
{
  const int b = blockIdx.x;
  if (b < 32)        wcvtNL_body(Wo, wTo, HID, HID, b);
  else if (b < 160)  wcvtNL_body(W1, wT1, HID, FFD, b - 32);
  else if (b < 288)  wcvtNL_body(W2, wT2, FFD, HID, b - 160);
  else if (b < 296)  csum512_body(W1, cs1, HID, FFD, b - 288);
  else if (b < 392) {
    const int i = b - 296, sel = i >> 5;
    const float* W = sel == 0 ? Wq : sel == 1 ? Wk : Wv;
    wcvtNL_body(W, wT3 + (size_t)sel*HID*HID, HID, HID, i & 31);
  } else {
    const int col = (b - 392)*512 + threadIdx.x;
    const int sel = col >> 10, n = col & 1023;
    const float* W = sel == 0 ? Wq : sel == 1 ? Wk : Wv;
    float s = 0.f;
    for (int k = 0; k < HID; ++k) s += W[(long)k*HID + n];
    cs3[col] = s;
  }
}

// ====== bf16 MFMA GEMM, 128x256 tile, BK=64, 8 waves, 32x32x16, LN-fold ====
// MODE 3: out = bf16( rstd*acc + (bias - mean*rstd*cs[col]) )          (QKV)
// MODE 4: out = bf16( relu(same) )                                     (FFN1)
// MODE 5: out = bf16( acc + bias + (res-mean)*rstd ); LN partials      (wo/FFN2)
template<int MODE>
__global__ __launch_bounds__(512, 4)
void gemmW(const bf16_t* __restrict__ A, const bf16_t* __restrict__ Bt,
           const float* __restrict__ ba, const float* __restrict__ bb,
           const float* __restrict__ bc, const float* __restrict__ cs,
           const float* __restrict__ partIn, int npIn,
           const bf16_t* __restrict__ res,
           bf16_t* __restrict__ outB, float* __restrict__ part,
           int M, int N, int K)
{
  __shared__ bf16_t As[128][64];
  __shared__ bf16_t Bs[256][64];
  __shared__ float  rs[512], rq[512];
  const int tid = threadIdx.x;
  const int w = tid >> 6, l = tid & 63;
  const int wm = w >> 2, wn = w & 3;
  const int lr = l & 31, hi = l >> 5;

  const int nbn = N >> 8;
  const int nwg = gridDim.x;
  const int q8 = nwg >> 3, r8 = nwg & 7;
  const int xcd = blockIdx.x & 7, bidx = blockIdx.x >> 3;
  const int wg = (xcd < r8 ? xcd*(q8+1) : r8*(q8+1) + (xcd-r8)*q8) + bidx;
  const long bm = wg / nbn, bn = wg % nbn;
  const long rA0 = bm << 7, rB0 = bn << 8;

  const int srow   = tid >> 3;
  const int schunk = (((tid & 7) ^ ((tid >> 3) & 7)) << 3);
  const int ldsw   = (tid >> 6) << 10;

  f32x16 a00 = {0}, a01 = {0}, a10 = {0}, a11 = {0};

#define STG_TILE(kt) do { \
    const long kb_ = (long)(kt)*64 + schunk; \
    gload_lds16(A  + (rA0 + srow)*(long)K + kb_,        (char*)As + ldsw); \
    gload_lds16(A  + (rA0 + 64 + srow)*(long)K + kb_,   (char*)As + 8192 + ldsw); \
    gload_lds16(Bt + (rB0 + srow)*(long)K + kb_,        (char*)Bs + ldsw); \
    gload_lds16(Bt + (rB0 + 64 + srow)*(long)K + kb_,   (char*)Bs + 8192 + ldsw); \
    gload_lds16(Bt + (rB0 + 128 + srow)*(long)K + kb_,  (char*)Bs + 16384 + ldsw); \
    gload_lds16(Bt + (rB0 + 192 + srow)*(long)K + kb_,  (char*)Bs + 24576 + ldsw); \
  } while (0)
#define FRA(mt, kk) (*(const bf16x8*)((const char*)As + (wm*64 + (mt)*32 + lr)*128 + \
                      ((((kk)*2 + hi) ^ (l & 7)) << 4)))
#define FRB(nt, kk) (*(const bf16x8*)((const char*)Bs + (wn*64 + (nt)*32 + lr)*128 + \
                      ((((kk)*2 + hi) ^ (l & 7)) << 4)))

  const int nk = K >> 6;
  for (int t = 0; t < nk; ++t) {
    __syncthreads();
    STG_TILE(t);
    __syncthreads();
#pragma unroll
    for (int kk = 0; kk < 4; ++kk) {
      bf16x8 fa0 = FRA(0, kk), fa1 = FRA(1, kk);
      bf16x8 fb0 = FRB(0, kk), fb1 = FRB(1, kk);
      a00 = __builtin_amdgcn_mfma_f32_32x32x16_bf16(fa0, fb0, a00, 0, 0, 0);
      a01 = __builtin_amdgcn_mfma_f32_32x32x16_bf16(fa0, fb1, a01, 0, 0, 0);
      a10 = __builtin_amdgcn_mfma_f32_32x32x16_bf16(fa1, fb0, a10, 0, 0, 0);
      a11 = __builtin_amdgcn_mfma_f32_32x32x16_bf16(fa1, fb1, a11, 0, 0, 0);
    }
  }
#undef STG_TILE
#undef FRA
#undef FRB

  // inline stats (reuses As as f64 scratch; barrier inside protects K-loop reads)
  float mS, rS;
  stats_reduce(partIn, npIn, (double*)&As[0][0], mS, rS, 512);

  const bool q3 = (N == 3072);
  float ls = 0.f, lsq = 0.f;
  const long rowT = rA0 + wm*64 + 4*hi;
  const long colT = rB0 + wn*64 + lr;
#pragma unroll
  for (int nt = 0; nt < 2; ++nt) {
    const long col = colT + nt*32;
    float bv;
    if (MODE == 3 && q3)
      bv = col < 1024 ? ba[col] : col < 2048 ? bb[col - 1024] : bc[col - 2048];
    else
      bv = ba[col];
    float beta = 0.f;
    if (MODE == 3 || MODE == 4) beta = bv - mS*rS*cs[col];
#pragma unroll
    for (int mt = 0; mt < 2; ++mt) {
      const f32x16 acc = mt == 0 ? (nt == 0 ? a00 : a01) : (nt == 0 ? a10 : a11);
#pragma unroll
      for (int r = 0; r < 16; ++r) {
        const long row = rowT + mt*32 + (r & 3) + 8*(r >> 2);
        const long off = row*(long)N + col;
        float v;
        if (MODE == 3)      v = fmaf(acc[r], rS, beta);
        else if (MODE == 4) v = fmaxf(fmaf(acc[r], rS, beta), 0.f);
        else {
          v = acc[r] + bv + ((float)res[off] - mS)*rS;
          ls += v; lsq += v*v;
        }
        outB[off] = (bf16_t)v;
      }
    }
  }
  if (MODE == 5) {
    rs[tid] = ls; rq[tid] = lsq;
    __syncthreads();
    for (int o = 256; o > 0; o >>= 1) {
      if (tid < o) { rs[tid] += rs[tid+o]; rq[tid] += rq[tid+o]; }
      __syncthreads();
    }
    if (tid == 0) { part[2*blockIdx.x] = rs[0]; part[2*blockIdx.x + 1] = rq[0]; }
  }
}

// ========== MFMA attention: one block per (b, head), 4 waves ===============
// Phase 1 (double-buffered): S = Q.K^T; raw s_barrier + counted vmcnt(8).
// Softmax in-register; P normalized to bf16 LDS. Phase 2: O = P.V with V
// transposed into LDS and next-chunk V register prefetch.
__global__ __launch_bounds__(256) void attn_m(
    const bf16_t* __restrict__ qkv, bf16_t* __restrict__ ob)
{
  __shared__ __align__(16) bf16_t Qb[2][8192];   // 32 KB
  __shared__ __align__(16) bf16_t Kb[2][8192];   // 32 KB
  __shared__ __align__(16) bf16_t Ps[4096];      // 8 KB
  bf16_t* Vs = &Qb[0][0];                        // [128][64] (phase 2)
  bf16_t* Os = &Kb[0][0];                        // [64][128] (phase 2)

  const int tid = threadIdx.x;
  const int w = tid >> 6, l = tid & 63;
  const int fr = l & 15, kq = l >> 4;
  const int head = blockIdx.x & 7, b = blockIdx.x >> 3;
  const long rbase = (long)head*32 + b;

  const int lr  = tid >> 2;                      // staging row 0..63
  const int sslot = (tid & 15) ^ (tid >> 4);     // pre-swizzled Q/K src slot

  f32x4 accS[4] = {{0,0,0,0},{0,0,0,0},{0,0,0,0},{0,0,0,0}};

#define STAGE_QK(qb, kb, kc) do { \
    _Pragma("unroll") for (int i_ = 0; i_ < 4; ++i_) { \
      const int r_ = i_*16 + (tid >> 4); \
      const long gq_ = ((long)r_*256 + rbase)*QKVS + (kc) + sslot*8; \
      gload_lds16(qkv + gq_,        (char*)(qb) + i_*4096 + w*1024); \
      gload_lds16(qkv + gq_ + 1024, (char*)(kb) + i_*4096 + w*1024); \
    } } while (0)

  // ---------------- phase 1: S = Q.K^T over K=1024, double-buffered --------
  STAGE_QK(Qb[0], Kb[0], 0);
#pragma unroll
  for (int c = 0; c < 8; ++c) {
    const int cur = c & 1;
    if (c < 7) {
      STAGE_QK(Qb[cur ^ 1], Kb[cur ^ 1], (c + 1)*128);
      asm volatile("s_waitcnt vmcnt(8)" ::: "memory");
    } else {
      asm volatile("s_waitcnt vmcnt(0)" ::: "memory");
    }
    BAR();                                       // chunk c resident
#pragma unroll
    for (int kk = 0; kk < 4; ++kk) {
      const int ra = w*16 + fr;
      bf16x8 a = *(const bf16x8*)&Qb[cur][ra*128 + (((kk*4 + kq) ^ fr) << 3)];
#pragma unroll
      for (int n = 0; n < 4; ++n) {
        const int rb = n*16 + fr;
        bf16x8 bv = *(const bf16x8*)&Kb[cur][rb*128 + (((kk*4 + kq) ^ fr) << 3)];
        accS[n] = __builtin_amdgcn_mfma_f32_16x16x32_bf16(a, bv, accS[n], 0, 0, 0);
      }
    }
    BAR();                                       // all reads done before restage
  }
#undef STAGE_QK

  // ---------------- softmax (rows live in 16-lane groups) ------------------
  const float scale = 0.08838834764831843f;      // 1/sqrt(128)
  float pj[4][4];
#pragma unroll
  for (int j = 0; j < 4; ++j) {
    float m = fmaxf(fmaxf(accS[0][j], accS[1][j]), fmaxf(accS[2][j], accS[3][j]));
    m = fmaxf(m, __shfl_xor(m, 1));
    m = fmaxf(m, __shfl_xor(m, 2));
    m = fmaxf(m, __shfl_xor(m, 4));
    m = fmaxf(m, __shfl_xor(m, 8));
    m *= scale;
    float s = 0.f;
#pragma unroll
    for (int n = 0; n < 4; ++n) { pj[n][j] = __expf(accS[n][j]*scale - m); s += pj[n][j]; }
    s += __shfl_xor(s, 1);
    s += __shfl_xor(s, 2);
    s += __shfl_xor(s, 4);
    s += __shfl_xor(s, 8);
    const float rv = 1.f / s;
#pragma unroll
    for (int n = 0; n < 4; ++n) pj[n][j] *= rv;
  }
#pragma unroll
  for (int n = 0; n < 4; ++n)
#pragma unroll
    for (int j = 0; j < 4; ++j) {
      const int r = w*16 + kq*4 + j;
      const int cpos = n*16 + fr;
      Ps[r*64 + (((cpos >> 3) ^ (r & 7)) << 3) + (cpos & 7)] = (bf16_t)pj[n][j];
    }
  __syncthreads();                               // P visible; Qb/Kb free

  // ---------------- phase 2: O = P.V, 128-feature chunks, V prefetch -------
  const long orow = (long)lr*256 + b*8 + head;
  const bf16_t* vbase = qkv + ((long)lr*256 + rbase)*QKVS + 2048;
  const int ra2 = w*16 + fr;
  bf16x8 a0 = *(const bf16x8*)&Ps[ra2*64 + ((kq       ^ (ra2 & 7)) << 3)];
  bf16x8 a1 = *(const bf16x8*)&Ps[ra2*64 + (((4 + kq) ^ (ra2 & 7)) << 3)];

  uint4 vr[4];
#pragma unroll
  for (int i = 0; i < 4; ++i)
    vr[i] = *(const uint4*)&vbase[(tid & 3)*8 + i*32];

#pragma unroll
  for (int fc8 = 0; fc8 < 8; ++fc8) {
    // transpose-write current V chunk into Vs[f][s] (slot-swizzled)
#pragma unroll
    for (int i = 0; i < 4; ++i) {
      const int f0 = (tid & 3)*8 + i*32;
      const bf16_t* ve = (const bf16_t*)&vr[i];
#pragma unroll
      for (int j = 0; j < 8; ++j) {
        const int f = f0 + j;
        Vs[f*64 + (((lr >> 3) ^ (f & 7)) << 3) + (lr & 7)] = ve[j];
      }
    }
    __syncthreads();
    // prefetch next chunk's V into registers (hides under MFMA+Os)
    if (fc8 < 7) {
#pragma unroll
      for (int i = 0; i < 4; ++i)
        vr[i] = *(const uint4*)&vbase[(fc8 + 1)*128 + (tid & 3)*8 + i*32];
    }
    f32x4 accO[8];
#pragma unroll
    for (int nt = 0; nt < 8; ++nt) {
      const int f = nt*16 + fr;
      bf16x8 b0 = *(const bf16x8*)&Vs[f*64 + ((kq       ^ (f & 7)) << 3)];
      bf16x8 b1 = *(const bf16x8*)&Vs[f*64 + (((4 + kq) ^ (f & 7)) << 3)];
      accO[nt] = __builtin_amdgcn_mfma_f32_16x16x32_bf16(a0, b0, (f32x4){0.f,0.f,0.f,0.f}, 0, 0, 0);
      accO[nt] = __builtin_amdgcn_mfma_f32_16x16x32_bf16(a1, b1, accO[nt], 0, 0, 0);
    }
#pragma unroll
    for (int nt = 0; nt < 8; ++nt)
#pragma unroll
      for (int j = 0; j < 4; ++j) {
        const int r = w*16 + kq*4 + j;
        const int cpos = nt*16 + fr;
        Os[r*128 + (((cpos >> 3) ^ (r & 7)) << 3) + (cpos & 7)] = (bf16_t)accO[nt][j];
      }
    __syncthreads();
#pragma unroll
    for (int i = 0; i < 4; ++i) {
      const int p = (tid & 3)*4 + i;             // logical 16B slot 0..15
      uint4 vv = *(const uint4*)&Os[lr*128 + ((p ^ (lr & 7)) << 3)];
      *(uint4*)&ob[orow*HID + fc8*128 + p*8] = vv;
    }
  }
}

// -------- final: d_out(f32) = (t2_raw - mean)*rstd (inline stats) ----------
__global__ __launch_bounds__(256) void final_norm(const bf16_t* __restrict__ t,
    const float* __restrict__ part, int np, float* __restrict__ out)
{
  __shared__ double shd[16];
  float m, r;
  stats_reduce(part, np, shd, m, r, 256);
  const long n8 = NTOT / 8;
  for (long i = (long)blockIdx.x*blockDim.x + threadIdx.x; i < n8;
       i += (long)gridDim.x*blockDim.x) {
    bf16x8 v = ((const bf16x8*)t)[i];
    float4 o0 = {((float)v[0]-m)*r, ((float)v[1]-m)*r, ((float)v[2]-m)*r, ((float)v[3]-m)*r};
    float4 o1 = {((float)v[4]-m)*r, ((float)v[5]-m)*r, ((float)v[6]-m)*r, ((float)v[7]-m)*r};
    ((float4*)out)[2*i]   = o0;
    ((float4*)out)[2*i+1] = o1;
  }
}

// ---------------------------------------------------------------------------
extern "C" void kernel_launch(void* const* d_in, const int* in_sizes, int n_in,
                              void* d_out, int out_size, void* d_ws, size_t ws_size,
                              hipStream_t stream)
{
  const int*   x    = (const int*)  d_in[0];
  const float* emb  = (const float*)d_in[1];
  const float* pos  = (const float*)d_in[2];
  const float* wq_a = (const float*)d_in[3];
  const float* bq_a = (const float*)d_in[4];
  const float* wk_a = (const float*)d_in[5];
  const float* bk_a = (const float*)d_in[6];
  const float* wv_a = (const float*)d_in[7];
  const float* bv_a = (const float*)d_in[8];
  const float* wo_a = (const float*)d_in[9];
  const float* bo_a = (const float*)d_in[10];
  const float* w1_a = (const float*)d_in[11];
  const float* b1_a = (const float*)d_in[12];
  const float* w2_a = (const float*)d_in[13];
  const float* b2_a = (const float*)d_in[14];

  char* p = (char*)d_ws;
  auto take = [&](size_t n) { char* r = p; p += (n + 255) & ~(size_t)255; return r; };
  bf16_t* hb   = (bf16_t*)take(NTOT*2);                 // raw hidden (rolling)
  bf16_t* U    = (bf16_t*)take((size_t)NROW*FFD*2);     // 128 MB union
  bf16_t* qkv  = U;                                     // NROW x 3072
  bf16_t* attb = U + 3*NTOT;
  bf16_t* ffb  = U;                                     // overlays qkv (dead)
  bf16_t* wTo  = (bf16_t*)take((size_t)HID*HID*2);
  bf16_t* wT1  = (bf16_t*)take((size_t)HID*FFD*2);
  bf16_t* wT2  = (bf16_t*)take((size_t)HID*FFD*2);
  bf16_t* wT3  = (bf16_t*)take((size_t)3*HID*HID*2);
  float*  cs1  = (float*) take(FFD*4);
  float*  cs3  = (float*) take(QKVS*4);
  float*  part1= (float*) take(2048*4);
  float*  part2= (float*) take(2048*4);

  const int gQKV = (NROW/128)*(QKVS/256);   // 1536
  const int gH   = (NROW/128)*(HID/256);    // 512
  const int gF   = (NROW/128)*(FFD/256);    // 2048

  embed_k<<<NROW, 256, 0, stream>>>(x, emb, pos, hb);
  prep0<<<102, 512, 0, stream>>>(wq_a, wk_a, wv_a, wT3, cs3);

  for (int i = 0; i < 6; ++i) {
    const float* Bq = bq_a + (size_t)i*HID;
    const float* Bk = bk_a + (size_t)i*HID;
    const float* Bv = bv_a + (size_t)i*HID;
    const float* Wo = wo_a + (size_t)i*HID*HID;  const float* Bo = bo_a + (size_t)i*HID;
    const float* W1 = w1_a + (size_t)i*HID*FFD;  const float* B1 = b1_a + (size_t)i*FFD;
    const float* W2 = w2_a + (size_t)i*FFD*HID;  const float* B2 = b2_a + (size_t)i*HID;
    const int npIn = (i == 0) ? 0 : gH;          // identity at layer 0
    const int haveNext = (i < 5);
    const float* Wqn = wq_a + (size_t)(i+1 < 6 ? i+1 : 0)*HID*HID;
    const float* Wkn = wk_a + (size_t)(i+1 < 6 ? i+1 : 0)*HID*HID;
    const float* Wvn = wv_a + (size_t)(i+1 < 6 ? i+1 : 0)*HID*HID;

    // QKV projection (LN-fold; stats inlined from part2)
    gemmW<3><<<gQKV, 512, 0, stream>>>(hb, wT3, Bq, Bk, Bv, cs3, part2, npIn,
                                       nullptr, qkv, nullptr, NROW, QKVS, HID);

    attn_m<<<256, 256, 0, stream>>>(qkv, attb);

    // standalone LDS-free weight prep for this layer (+ next-layer QKV)
    prep_k<<<haveNext ? 398 : 296, 512, 0, stream>>>(
        Wo, wTo, W1, wT1, cs1, W2, wT2, Wqn, Wkn, Wvn, wT3, cs3);

    // wo projection + residual fold + LN partials -> part1
    gemmW<5><<<gH, 512, 0, stream>>>(attb, wTo, Bo, Bo, Bo, nullptr, part2, npIn,
                                     hb, hb, part1, NROW, HID, HID);

    // FFN1 (LN-fold + relu; stats from part1)
    gemmW<4><<<gF, 512, 0, stream>>>(hb, wT1, B1, B1, B1, cs1, part1, gH,
                                     nullptr, ffb, nullptr, NROW, FFD, HID);

    // FFN2 + residual fold + LN partials -> part2
    gemmW<5><<<gH, 512, 0, stream>>>(ffb, wT2, B2, B2, B2, nullptr, part1, gH,
                                     hb, hb, part2, NROW, HID, FFD);
  }

  final_norm<<<2048, 256, 0, stream>>>(hb, part2, gH, (float*)d_out);
}